// Round 6
// baseline (14406.131 us; speedup 1.0000x reference)
//
#include <hip/hip_runtime.h>

typedef __attribute__((ext_vector_type(8))) short short8;
typedef __attribute__((ext_vector_type(4))) float f32x4;
typedef __attribute__((ext_vector_type(4))) unsigned short u16x4;
typedef __attribute__((ext_vector_type(8))) unsigned short u16x8;

#define S_ 512
#define B_ 64
#define E_ 256
#define H_ 256
#define NSTEP 1023  // 2*S - 1 sequential cell steps per chain

// ---------- helpers ----------
__device__ __forceinline__ unsigned short f2bf(float f) {
  unsigned u = __builtin_bit_cast(unsigned, f);
  return (unsigned short)((u + 0x7fffu + ((u >> 16) & 1u)) >> 16);  // RNE
}
__device__ __forceinline__ float bf2f(unsigned short h) {
  unsigned u = ((unsigned)h) << 16;
  return __builtin_bit_cast(float, u);
}
__device__ __forceinline__ float sigm(float x) { return 1.f / (1.f + __expf(-x)); }
__device__ __forceinline__ float tanh_(float x) {
  x = fminf(fmaxf(x, -15.f), 15.f);
  float e = __expf(-2.f * x);
  return (1.f - e) / (1.f + e);
}

// ---------- prep ----------
// x -> bf16; wx packed rows p=jc*4+gate, natural cols; wh packed rows, PERMUTED cols:
// stored col k holds orig col (k&~15)|((k&3)<<2)|((k>>2)&3); bias combined.
__global__ __launch_bounds__(256) void prep3(
    const float* __restrict__ x,
    const float* __restrict__ wih_f, const float* __restrict__ whh_f,
    const float* __restrict__ bih_f, const float* __restrict__ bhh_f,
    const float* __restrict__ wih_b, const float* __restrict__ whh_b,
    const float* __restrict__ bih_b, const float* __restrict__ bhh_b,
    short* __restrict__ x_bf, short* __restrict__ wx, short* __restrict__ wh,
    float* __restrict__ bias_p)
{
  long i0 = (long)blockIdx.x * blockDim.x + threadIdx.x;
  long stride = (long)gridDim.x * blockDim.x;
  const long NX = (long)S_ * B_ * E_;
  const long NW = 2L * 1024 * 256;
  const long NB = 2L * 1024;

  for (long i = i0; i < NX; i += stride) x_bf[i] = (short)f2bf(x[i]);

  for (long i = i0; i < NW; i += stride) {
    int ch  = (int)(i >> 18);
    int rem = (int)(i & 262143);
    int p   = rem >> 8;
    int k   = rem & 255;
    int jc  = p >> 2, g = p & 3;
    long j  = (long)(g * 256 + jc);
    int ko  = (k & ~15) | ((k & 3) << 2) | ((k >> 2) & 3);
    wx[i] = (short)f2bf((ch ? wih_b : wih_f)[j * 256 + k]);
    wh[i] = (short)f2bf((ch ? whh_b : whh_f)[j * 256 + ko]);
  }

  for (long i = i0; i < NB; i += stride) {
    int ch = (int)(i >> 10);
    int p  = (int)(i & 1023);
    int jc = p >> 2, g = p & 3;
    int j  = g * 256 + jc;
    bias_p[i] = ch ? (bih_b[j] + bhh_b[j]) : (bih_f[j] + bhh_f[j]);
  }
}

// ---------- xz precompute (bias folded), bf16 ----------
// layout: xz[ch][t][wl 16][b 64][ll 4][ml 4][g 4], jc = wl*16 + ml*4 + ll
__global__ __launch_bounds__(512, 2) void xz_gemm3(
    const short* __restrict__ x_bf, const short* __restrict__ wx,
    const float* __restrict__ bias_p, short* __restrict__ xz)
{
  const int bid = blockIdx.x;
  const int ch = bid >> 9, t = bid & 511;
  const int tid = threadIdx.x;
  const int wave = tid >> 6, lane = tid & 63;
  const int l15 = lane & 15, l4 = lane >> 4;

  const short* W = wx + (long)ch * 1024 * 256;
  const short* X = x_bf + (long)t * B_ * E_;

  f32x4 acc[8][4];
#pragma unroll
  for (int mt = 0; mt < 8; ++mt)
#pragma unroll
    for (int nt = 0; nt < 4; ++nt) acc[mt][nt] = (f32x4){0.f, 0.f, 0.f, 0.f};

#pragma unroll
  for (int ks = 0; ks < 8; ++ks) {
    int k0 = ks * 32 + l4 * 8;
    short8 bfr[4];
#pragma unroll
    for (int nt = 0; nt < 4; ++nt)
      bfr[nt] = *(const short8*)(X + (long)(nt * 16 + l15) * E_ + k0);
#pragma unroll
    for (int mt = 0; mt < 8; ++mt) {
      int p = (wave * 8 + mt) * 16 + l15;
      short8 af = *(const short8*)(W + (long)p * 256 + k0);
#pragma unroll
      for (int nt = 0; nt < 4; ++nt)
        acc[mt][nt] = __builtin_amdgcn_mfma_f32_16x16x32_bf16(af, bfr[nt], acc[mt][nt], 0, 0, 0);
    }
  }

#pragma unroll
  for (int mt = 0; mt < 8; ++mt) {
    int jc = (wave * 8 + mt) * 4 + l4;
    int wl = jc >> 4, ml = (jc >> 2) & 3, ll = jc & 3;
    f32x4 b4 = *(const f32x4*)(bias_p + ch * 1024 + jc * 4);
#pragma unroll
    for (int nt = 0; nt < 4; ++nt) {
      int b = nt * 16 + l15;
      u16x4 v;
#pragma unroll
      for (int g = 0; g < 4; ++g) v[g] = f2bf(acc[mt][nt][g] + b4[g]);
      long off = ((((long)ch * 512 + t) * 16 + wl) * 64 + b) * 64 + ll * 16 + ml * 4;
      *(u16x4*)(xz + off) = v;
    }
  }
}

// ---------- v6 LSTM: 8 waves; weights: 4 tiles AGPR + 2 LDS + 2 L2-streamed ----------
// grid 8: ch = bid>>2, batch-slice bs = bid&3 (16 cols). 512 threads.
// Weight tiles mt0-3 pinned in AGPRs ("a" class) — gfx950 MFMA sources A from AGPR
// directly; arch-VGPR demand drops under the 128 cap -> no scratch spills.
__global__ __attribute__((amdgpu_flat_work_group_size(512, 512)))
__attribute__((amdgpu_waves_per_eu(2, 2))) void lstm6(
    const short* __restrict__ wh, const short* __restrict__ xz,
    float* __restrict__ out)
{
  const int ch = blockIdx.x >> 2;
  const int bs = blockIdx.x & 3;
  const int tid = threadIdx.x;
  const int wave = tid >> 6, lane = tid & 63;
  const int l15 = lane & 15, l4 = lane >> 4;
  const int bloc = l15;
  const int bglob = bs * 16 + l15;
  const int swz = (l15 & 7) << 4;

  __shared__ short w_lds[8 * 2 * 16 * 256];  // 128 KB: per wave tiles mt=4,5 (rows +64..95)
  __shared__ short h_lds[2 * 16 * 256];      // 16 KB double buffer

  const short* whc = wh + (long)ch * 1024 * 256;

  // ---- stage LDS tiles (rows wave*128+64 .. +95), swizzled; zero h ----
  {
    char* wl = (char*)w_lds;
#pragma unroll
    for (int c = 0; c < 16; ++c) {
      int idx = c * 64 + lane;
      int row = idx >> 5;            // 0..31
      int c16 = idx & 31;
      short8 v = *(const short8*)(whc + (long)(wave * 128 + 64 + row) * 256 + c16 * 8);
      int boff = wave * 16384 + row * 512 + ((c16 * 16) ^ ((row & 7) << 4));
      *(short8*)(wl + boff) = v;
    }
    for (int i = tid; i < 2 * 16 * 256; i += 512) h_lds[i] = 0;
  }

  // ---- weight tiles mt 0..3 (rows wave*128 + mt*16) -> AGPRs ----
  short8 ah[4][8];
#pragma unroll
  for (int mt = 0; mt < 4; ++mt)
#pragma unroll
    for (int ks = 0; ks < 8; ++ks)
      ah[mt][ks] = *(const short8*)(whc + (long)(wave * 128 + mt * 16 + l15) * 256 + ks * 32 + l4 * 8);
#pragma unroll
  for (int mt = 0; mt < 4; ++mt)
#pragma unroll
    for (int ks = 0; ks < 8; ++ks)
      asm volatile("" : "+a"(ah[mt][ks]));   // pin to AGPR class (accumulator file)

  // ---- L2-stream bases: tiles mt=6 (rows +96) and mt=7 (rows +112) ----
  const short* w6b = whc + (long)(wave * 128 + 96 + l15) * 256 + l4 * 8;
  const short* w7b = whc + (long)(wave * 128 + 112 + l15) * 256 + l4 * 8;
  const short* xzb = xz + (((long)ch * 512 * 16 + 2 * wave) * 4096) + bglob * 64 + l4 * 16;

  float cst[8], hmax[8];
#pragma unroll
  for (int mt = 0; mt < 8; ++mt) { cst[mt] = 0.f; hmax[mt] = -2.f; }

  __syncthreads();

  const char* hlr = (const char*)h_lds;
  const char* wlc = (const char*)w_lds + wave * 16384 + l15 * 512;
  char* hlw = (char*)h_lds;
  int soff = 0;  // opaque per-iteration: defeats LICM on stream loads

  for (int t = 0; t < NSTEP; ++t) {
    int tok;
    if (ch == 0) tok = (t + 1) >> 1;
    else         tok = (t == NSTEP - 1) ? (S_ - 1) : ((t & 1) ? (t >> 1) : (t >> 1) + 1);

    // re-pin: loop-carried AGPR residency (asm def each iteration)
#pragma unroll
    for (int mt = 0; mt < 4; ++mt)
#pragma unroll
      for (int ks = 0; ks < 8; ++ks)
        asm volatile("" : "+a"(ah[mt][ks]));

    asm volatile("" : "+v"(soff));
    const short* p6 = w6b + soff;
    const short* p7 = w7b + soff;

    // xz addends first (L3 latency is longest; consumed at gate phase)
    const short* xp = xzb + (long)tok * 65536;
    u16x8 xq0 = *(const u16x8*)(xp);
    u16x8 xq1 = *(const u16x8*)(xp + 8);
    u16x8 xq2 = *(const u16x8*)(xp + 4096);
    u16x8 xq3 = *(const u16x8*)(xp + 4104);

    // stream batch 1 (ks 0..3)
    short8 s6[4], s7[4];
#pragma unroll
    for (int k = 0; k < 4; ++k) {
      s6[k] = *(const short8*)(p6 + k * 32);
      s7[k] = *(const short8*)(p7 + k * 32);
    }

    f32x4 acc[8];
#pragma unroll
    for (int mt = 0; mt < 8; ++mt) acc[mt] = (f32x4){0.f, 0.f, 0.f, 0.f};

    const int pr = ((t + 1) & 1) * 8192;

    // ---- phase A: ks 0..3 ----
#pragma unroll
    for (int ks = 0; ks < 4; ++ks) {
      int koff = ks * 64 + l4 * 16;
      short8 hfr = *(const short8*)(hlr + pr + bloc * 512 + (koff ^ swz));
      short8 w4  = *(const short8*)(wlc + (koff ^ swz));
      short8 w5  = *(const short8*)(wlc + 8192 + (koff ^ swz));
      acc[0] = __builtin_amdgcn_mfma_f32_16x16x32_bf16(ah[0][ks], hfr, acc[0], 0, 0, 0);
      acc[1] = __builtin_amdgcn_mfma_f32_16x16x32_bf16(ah[1][ks], hfr, acc[1], 0, 0, 0);
      acc[2] = __builtin_amdgcn_mfma_f32_16x16x32_bf16(ah[2][ks], hfr, acc[2], 0, 0, 0);
      acc[3] = __builtin_amdgcn_mfma_f32_16x16x32_bf16(ah[3][ks], hfr, acc[3], 0, 0, 0);
      acc[4] = __builtin_amdgcn_mfma_f32_16x16x32_bf16(w4, hfr, acc[4], 0, 0, 0);
      acc[5] = __builtin_amdgcn_mfma_f32_16x16x32_bf16(w5, hfr, acc[5], 0, 0, 0);
      acc[6] = __builtin_amdgcn_mfma_f32_16x16x32_bf16(s6[ks], hfr, acc[6], 0, 0, 0);
      acc[7] = __builtin_amdgcn_mfma_f32_16x16x32_bf16(s7[ks], hfr, acc[7], 0, 0, 0);
    }

    // stream batch 2 (ks 4..7) — batch-1 regs dead, reuse
    short8 t6[4], t7[4];
#pragma unroll
    for (int k = 0; k < 4; ++k) {
      t6[k] = *(const short8*)(p6 + 128 + k * 32);
      t7[k] = *(const short8*)(p7 + 128 + k * 32);
    }

    // ---- phase B: ks 4..7 ----
#pragma unroll
    for (int ks = 4; ks < 8; ++ks) {
      int koff = ks * 64 + l4 * 16;
      short8 hfr = *(const short8*)(hlr + pr + bloc * 512 + (koff ^ swz));
      short8 w4  = *(const short8*)(wlc + (koff ^ swz));
      short8 w5  = *(const short8*)(wlc + 8192 + (koff ^ swz));
      acc[0] = __builtin_amdgcn_mfma_f32_16x16x32_bf16(ah[0][ks], hfr, acc[0], 0, 0, 0);
      acc[1] = __builtin_amdgcn_mfma_f32_16x16x32_bf16(ah[1][ks], hfr, acc[1], 0, 0, 0);
      acc[2] = __builtin_amdgcn_mfma_f32_16x16x32_bf16(ah[2][ks], hfr, acc[2], 0, 0, 0);
      acc[3] = __builtin_amdgcn_mfma_f32_16x16x32_bf16(ah[3][ks], hfr, acc[3], 0, 0, 0);
      acc[4] = __builtin_amdgcn_mfma_f32_16x16x32_bf16(w4, hfr, acc[4], 0, 0, 0);
      acc[5] = __builtin_amdgcn_mfma_f32_16x16x32_bf16(w5, hfr, acc[5], 0, 0, 0);
      acc[6] = __builtin_amdgcn_mfma_f32_16x16x32_bf16(t6[ks - 4], hfr, acc[6], 0, 0, 0);
      acc[7] = __builtin_amdgcn_mfma_f32_16x16x32_bf16(t7[ks - 4], hfr, acc[7], 0, 0, 0);
    }

    // ---- gates / state / h write ----
    unsigned short hv[8];
#pragma unroll
    for (int mt = 0; mt < 8; ++mt) {
      const u16x8& q = (mt < 2) ? xq0 : (mt < 4) ? xq1 : (mt < 6) ? xq2 : xq3;
      const int o = (mt & 1) * 4;
      float zi = acc[mt][0] + bf2f(q[o]);
      float zf = acc[mt][1] + bf2f(q[o + 1]);
      float zg = acc[mt][2] + bf2f(q[o + 2]);
      float zo = acc[mt][3] + bf2f(q[o + 3]);
      float cc = cst[mt];
      cc = sigm(zf) * cc + sigm(zi) * tanh_(zg);
      float hh = sigm(zo) * tanh_(cc);
      cst[mt] = cc;
      hmax[mt] = fmaxf(hmax[mt], hh);
      hv[mt] = f2bf(hh);
    }
    {
      char* hw = hlw + (t & 1) * 8192 + bloc * 512;
      u16x4 a = {hv[0], hv[1], hv[2], hv[3]};
      u16x4 b = {hv[4], hv[5], hv[6], hv[7]};
      *(u16x4*)(hw + ((wave * 64 + l4 * 8) ^ swz)) = a;
      *(u16x4*)(hw + ((wave * 64 + l4 * 8 + 32) ^ swz)) = b;
    }

    __syncthreads();
  }

#pragma unroll
  for (int mt = 0; mt < 8; ++mt) {
    int jc = wave * 32 + mt * 4 + l4;
    out[(long)bglob * (2 * H_) + ch * H_ + jc] = hmax[mt];
  }
}

// ---------- fallback (no xz workspace): v3 structure, MODE 0 ----------
__global__ __launch_bounds__(1024, 4) void lstm_fb(
    const short* __restrict__ x_bf, const short* __restrict__ wx,
    const short* __restrict__ wh, const float* __restrict__ bias_p,
    float* __restrict__ out)
{
  const int ch = blockIdx.x >> 2;
  const int bs = blockIdx.x & 3;
  const int tid = threadIdx.x;
  const int wave = tid >> 6, lane = tid & 63;
  const int l15 = lane & 15, l4 = lane >> 4;
  const int bloc = l15;
  const int bglob = bs * 16 + l15;

  __shared__ short w_lds[16 * 16 * 256];
  __shared__ short h_lds[2 * 16 * 256];

  const short* whc = wh + (long)ch * 1024 * 256;
  const short* wxc = wx + (long)ch * 1024 * 256;

  {
    char* wl = (char*)w_lds;
#pragma unroll
    for (int c = 0; c < 8; ++c) {
      int chunk = c * 64 + lane;
      int row = chunk >> 5;
      int c16 = chunk & 31;
      short8 v = *(const short8*)(whc + (long)(wave * 64 + 48 + row) * 256 + c16 * 8);
      int boff = wave * 8192 + row * 512 + ((c16 * 16) ^ ((row & 7) << 4));
      *(short8*)(wl + boff) = v;
    }
    for (int i = tid; i < 2 * 16 * 256; i += 1024) h_lds[i] = 0;
  }

  short8 ah[3][8];
#pragma unroll
  for (int mt = 0; mt < 3; ++mt)
#pragma unroll
    for (int ks = 0; ks < 8; ++ks)
      ah[mt][ks] = *(const short8*)(whc + (long)(wave * 64 + mt * 16 + l15) * 256 + ks * 32 + l4 * 8);

  f32x4 bias4v[4];
#pragma unroll
  for (int mt = 0; mt < 4; ++mt)
    bias4v[mt] = *(const f32x4*)(bias_p + ch * 1024 + (wave * 16 + mt * 4 + l4) * 4);

  float cst[4], hmax[4];
#pragma unroll
  for (int mt = 0; mt < 4; ++mt) { cst[mt] = 0.f; hmax[mt] = -2.f; }

  __syncthreads();

  const char* hlr = (const char*)h_lds;
  const char* wlr = (const char*)w_lds;
  char* hlw = (char*)h_lds;
  const int swzb = (bloc & 7) << 4;
  const int wboff = wave * 8192 + l15 * 512;
  const int q0b = (wave * 16 + l4 * 4) * 2;

  for (int t = 0; t < NSTEP; ++t) {
    int tok;
    if (ch == 0) tok = (t + 1) >> 1;
    else         tok = (t == NSTEP - 1) ? (S_ - 1) : ((t & 1) ? (t >> 1) : (t >> 1) + 1);

    f32x4 acc[4];
#pragma unroll
    for (int mt = 0; mt < 4; ++mt) acc[mt] = (f32x4){0.f, 0.f, 0.f, 0.f};

    const short* xr = x_bf + ((long)tok * B_ + bglob) * E_;
#pragma unroll
    for (int ks = 0; ks < 8; ++ks) {
      int k0 = ks * 32 + l4 * 8;
      short8 bx = *(const short8*)(xr + k0);
#pragma unroll
      for (int mt = 0; mt < 4; ++mt) {
        short8 axf = *(const short8*)(wxc + (long)(wave * 64 + mt * 16 + l15) * 256 + k0);
        acc[mt] = __builtin_amdgcn_mfma_f32_16x16x32_bf16(axf, bx, acc[mt], 0, 0, 0);
      }
    }

    const int hbase = (((t + 1) & 1) * 8192) + bloc * 512;
#pragma unroll
    for (int ks = 0; ks < 8; ++ks) {
      int koff = ks * 64 + l4 * 16;
      short8 hfr = *(const short8*)(hlr + hbase + (koff ^ swzb));
      acc[0] = __builtin_amdgcn_mfma_f32_16x16x32_bf16(ah[0][ks], hfr, acc[0], 0, 0, 0);
      acc[1] = __builtin_amdgcn_mfma_f32_16x16x32_bf16(ah[1][ks], hfr, acc[1], 0, 0, 0);
      acc[2] = __builtin_amdgcn_mfma_f32_16x16x32_bf16(ah[2][ks], hfr, acc[2], 0, 0, 0);
      short8 wfr = *(const short8*)(wlr + wboff + (koff ^ ((l15 & 7) << 4)));
      acc[3] = __builtin_amdgcn_mfma_f32_16x16x32_bf16(wfr, hfr, acc[3], 0, 0, 0);
    }

    unsigned short hv[4];
#pragma unroll
    for (int mt = 0; mt < 4; ++mt) {
      float zi = acc[mt][0] + bias4v[mt][0];
      float zf = acc[mt][1] + bias4v[mt][1];
      float zg = acc[mt][2] + bias4v[mt][2];
      float zo = acc[mt][3] + bias4v[mt][3];
      float cc = cst[mt];
      cc = sigm(zf) * cc + sigm(zi) * tanh_(zg);
      float hh = sigm(zo) * tanh_(cc);
      cst[mt] = cc;
      hmax[mt] = fmaxf(hmax[mt], hh);
      hv[mt] = f2bf(hh);
    }
    {
      u16x4 hw4 = {hv[0], hv[1], hv[2], hv[3]};
      int wb = ((t & 1) * 8192) + bloc * 512 + (q0b ^ swzb);
      *(u16x4*)(hlw + wb) = hw4;
    }

    __syncthreads();
  }

#pragma unroll
  for (int mt = 0; mt < 4; ++mt) {
    int jc = wave * 16 + mt * 4 + l4;
    out[(long)bglob * (2 * H_) + ch * H_ + jc] = hmax[mt];
  }
}

extern "C" void kernel_launch(void* const* d_in, const int* in_sizes, int n_in,
                              void* d_out, int out_size, void* d_ws, size_t ws_size,
                              hipStream_t stream) {
  const float* x     = (const float*)d_in[0];
  const float* wih_f = (const float*)d_in[1];
  const float* whh_f = (const float*)d_in[2];
  const float* bih_f = (const float*)d_in[3];
  const float* bhh_f = (const float*)d_in[4];
  const float* wih_b = (const float*)d_in[5];
  const float* whh_b = (const float*)d_in[6];
  const float* bih_b = (const float*)d_in[7];
  const float* bhh_b = (const float*)d_in[8];

  char* ws = (char*)d_ws;
  short* x_bf   = (short*)(ws);                 // 16,777,216 B
  short* wx     = (short*)(ws + 16777216);      //  1,048,576 B
  short* wh     = (short*)(ws + 17825792);      //  1,048,576 B
  float* bias_p = (float*)(ws + 18874368);      //      8,192 B
  short* xz     = (short*)(ws + 18882560);      // 134,217,728 B (bf16)

  const size_t NEED_XZ = 18882560UL + 134217728UL;   // 153,100,288
  if (ws_size < 18882560UL) return;

  prep3<<<2048, 256, 0, stream>>>(x, wih_f, whh_f, bih_f, bhh_f,
                                  wih_b, whh_b, bih_b, bhh_b,
                                  x_bf, wx, wh, bias_p);

  float* outp = (float*)d_out;
  if (ws_size >= NEED_XZ) {
    xz_gemm3<<<1024, 512, 0, stream>>>(x_bf, wx, bias_p, xz);
    lstm6<<<8, 512, 0, stream>>>(wh, xz, outp);
  } else {
    lstm_fb<<<8, 1024, 0, stream>>>(x_bf, wx, wh, bias_p, outp);
  }
}

// Round 7
// 7953.303 us; speedup vs baseline: 1.8113x; 1.8113x over previous
//
#include <hip/hip_runtime.h>

typedef __attribute__((ext_vector_type(8))) short short8;
typedef __attribute__((ext_vector_type(4))) float f32x4;
typedef __attribute__((ext_vector_type(4))) unsigned short u16x4;
typedef __attribute__((ext_vector_type(8))) unsigned short u16x8;

#define S_ 512
#define B_ 64
#define E_ 256
#define H_ 256
#define NSTEP 1023  // 2*S - 1 sequential cell steps per chain

// ---------- helpers ----------
__device__ __forceinline__ unsigned short f2bf(float f) {
  unsigned u = __builtin_bit_cast(unsigned, f);
  return (unsigned short)((u + 0x7fffu + ((u >> 16) & 1u)) >> 16);  // RNE
}
__device__ __forceinline__ float bf2f(unsigned short h) {
  unsigned u = ((unsigned)h) << 16;
  return __builtin_bit_cast(float, u);
}
__device__ __forceinline__ float sigm(float x) { return 1.f / (1.f + __expf(-x)); }
__device__ __forceinline__ float tanh_(float x) {
  x = fminf(fmaxf(x, -15.f), 15.f);
  float e = __expf(-2.f * x);
  return (1.f - e) / (1.f + e);
}

// MFMA with A-operand pinned to the AGPR file (no a->v copies possible).
__device__ __forceinline__ void mfma_ag(f32x4& acc, const short8& a_agpr, const short8& b) {
  asm("v_mfma_f32_16x16x32_bf16 %0, %1, %2, %0" : "+v"(acc) : "a"(a_agpr), "v"(b));
}

// ---------- prep ----------
// x -> bf16; wx packed rows p=jc*4+gate, natural cols; wh packed rows, PERMUTED cols:
// stored col k holds orig col (k&~15)|((k&3)<<2)|((k>>2)&3); bias combined.
__global__ __launch_bounds__(256) void prep3(
    const float* __restrict__ x,
    const float* __restrict__ wih_f, const float* __restrict__ whh_f,
    const float* __restrict__ bih_f, const float* __restrict__ bhh_f,
    const float* __restrict__ wih_b, const float* __restrict__ whh_b,
    const float* __restrict__ bih_b, const float* __restrict__ bhh_b,
    short* __restrict__ x_bf, short* __restrict__ wx, short* __restrict__ wh,
    float* __restrict__ bias_p)
{
  long i0 = (long)blockIdx.x * blockDim.x + threadIdx.x;
  long stride = (long)gridDim.x * blockDim.x;
  const long NX = (long)S_ * B_ * E_;
  const long NW = 2L * 1024 * 256;
  const long NB = 2L * 1024;

  for (long i = i0; i < NX; i += stride) x_bf[i] = (short)f2bf(x[i]);

  for (long i = i0; i < NW; i += stride) {
    int ch  = (int)(i >> 18);
    int rem = (int)(i & 262143);
    int p   = rem >> 8;
    int k   = rem & 255;
    int jc  = p >> 2, g = p & 3;
    long j  = (long)(g * 256 + jc);
    int ko  = (k & ~15) | ((k & 3) << 2) | ((k >> 2) & 3);
    wx[i] = (short)f2bf((ch ? wih_b : wih_f)[j * 256 + k]);
    wh[i] = (short)f2bf((ch ? whh_b : whh_f)[j * 256 + ko]);
  }

  for (long i = i0; i < NB; i += stride) {
    int ch = (int)(i >> 10);
    int p  = (int)(i & 1023);
    int jc = p >> 2, g = p & 3;
    int j  = g * 256 + jc;
    bias_p[i] = ch ? (bih_b[j] + bhh_b[j]) : (bih_f[j] + bhh_f[j]);
  }
}

// ---------- xz precompute (bias folded), bf16 ----------
// layout: xz[ch][t][wl 16][b 64][ll 4][ml 4][g 4], jc = wl*16 + ml*4 + ll
__global__ __launch_bounds__(512, 2) void xz_gemm3(
    const short* __restrict__ x_bf, const short* __restrict__ wx,
    const float* __restrict__ bias_p, short* __restrict__ xz)
{
  const int bid = blockIdx.x;
  const int ch = bid >> 9, t = bid & 511;
  const int tid = threadIdx.x;
  const int wave = tid >> 6, lane = tid & 63;
  const int l15 = lane & 15, l4 = lane >> 4;

  const short* W = wx + (long)ch * 1024 * 256;
  const short* X = x_bf + (long)t * B_ * E_;

  f32x4 acc[8][4];
#pragma unroll
  for (int mt = 0; mt < 8; ++mt)
#pragma unroll
    for (int nt = 0; nt < 4; ++nt) acc[mt][nt] = (f32x4){0.f, 0.f, 0.f, 0.f};

#pragma unroll
  for (int ks = 0; ks < 8; ++ks) {
    int k0 = ks * 32 + l4 * 8;
    short8 bfr[4];
#pragma unroll
    for (int nt = 0; nt < 4; ++nt)
      bfr[nt] = *(const short8*)(X + (long)(nt * 16 + l15) * E_ + k0);
#pragma unroll
    for (int mt = 0; mt < 8; ++mt) {
      int p = (wave * 8 + mt) * 16 + l15;
      short8 af = *(const short8*)(W + (long)p * 256 + k0);
#pragma unroll
      for (int nt = 0; nt < 4; ++nt)
        acc[mt][nt] = __builtin_amdgcn_mfma_f32_16x16x32_bf16(af, bfr[nt], acc[mt][nt], 0, 0, 0);
    }
  }

#pragma unroll
  for (int mt = 0; mt < 8; ++mt) {
    int jc = (wave * 8 + mt) * 4 + l4;
    int wl = jc >> 4, ml = (jc >> 2) & 3, ll = jc & 3;
    f32x4 b4 = *(const f32x4*)(bias_p + ch * 1024 + jc * 4);
#pragma unroll
    for (int nt = 0; nt < 4; ++nt) {
      int b = nt * 16 + l15;
      u16x4 v;
#pragma unroll
      for (int g = 0; g < 4; ++g) v[g] = f2bf(acc[mt][nt][g] + b4[g]);
      long off = ((((long)ch * 512 + t) * 16 + wl) * 64 + b) * 64 + ll * 16 + ml * 4;
      *(u16x4*)(xz + off) = v;
    }
  }
}

// ---------- v7 LSTM: 8 waves; weights: 4 tiles AGPR (asm-consumed) + 2 LDS + 2 L2 ----------
// grid 8: ch = bid>>2, batch-slice bs = bid&3 (16 cols). 512 threads.
// ah pinned to AGPR ONCE before the loop; all uses are asm MFMA with "a" input
// constraint -> zero per-step copies; arch-VGPR demand ~120 <= 128 cap.
__global__ __attribute__((amdgpu_flat_work_group_size(512, 512)))
__attribute__((amdgpu_waves_per_eu(2, 2))) void lstm7(
    const short* __restrict__ wh, const short* __restrict__ xz,
    float* __restrict__ out)
{
  const int ch = blockIdx.x >> 2;
  const int bs = blockIdx.x & 3;
  const int tid = threadIdx.x;
  const int wave = tid >> 6, lane = tid & 63;
  const int l15 = lane & 15, l4 = lane >> 4;
  const int bloc = l15;
  const int bglob = bs * 16 + l15;
  const int swz = (l15 & 7) << 4;

  __shared__ short w_lds[8 * 2 * 16 * 256];  // 128 KB: per wave tiles mt=4,5 (rows +64..95)
  __shared__ short h_lds[2 * 16 * 256];      // 16 KB double buffer

  const short* whc = wh + (long)ch * 1024 * 256;

  // ---- stage LDS tiles (rows wave*128+64 .. +95), swizzled; zero h ----
  {
    char* wl = (char*)w_lds;
#pragma unroll
    for (int c = 0; c < 16; ++c) {
      int idx = c * 64 + lane;
      int row = idx >> 5;            // 0..31
      int c16 = idx & 31;
      short8 v = *(const short8*)(whc + (long)(wave * 128 + 64 + row) * 256 + c16 * 8);
      int boff = wave * 16384 + row * 512 + ((c16 * 16) ^ ((row & 7) << 4));
      *(short8*)(wl + boff) = v;
    }
    for (int i = tid; i < 2 * 16 * 256; i += 512) h_lds[i] = 0;
  }

  // ---- weight tiles mt 0..3 (rows wave*128 + mt*16): load, then ONE-TIME AGPR pin ----
  short8 ah[4][8];
#pragma unroll
  for (int mt = 0; mt < 4; ++mt)
#pragma unroll
    for (int ks = 0; ks < 8; ++ks)
      ah[mt][ks] = *(const short8*)(whc + (long)(wave * 128 + mt * 16 + l15) * 256 + ks * 32 + l4 * 8);
#pragma unroll
  for (int mt = 0; mt < 4; ++mt)
#pragma unroll
    for (int ks = 0; ks < 8; ++ks)
      asm volatile("" : "+a"(ah[mt][ks]));   // one-time: home in AGPR, opaque origin

  // ---- L2-stream bases: tiles mt=6 (rows +96) and mt=7 (rows +112) ----
  const short* w6b = whc + (long)(wave * 128 + 96 + l15) * 256 + l4 * 8;
  const short* w7b = whc + (long)(wave * 128 + 112 + l15) * 256 + l4 * 8;
  const short* xzb = xz + (((long)ch * 512 * 16 + 2 * wave) * 4096) + bglob * 64 + l4 * 16;

  float cst[8], hmax[8];
#pragma unroll
  for (int mt = 0; mt < 8; ++mt) { cst[mt] = 0.f; hmax[mt] = -2.f; }

  __syncthreads();

  const char* hlr = (const char*)h_lds;
  const char* wlc = (const char*)w_lds + wave * 16384 + l15 * 512;
  char* hlw = (char*)h_lds;
  int soff = 0;  // opaque (SGPR): defeats LICM on the per-step weight re-stream

  for (int t = 0; t < NSTEP; ++t) {
    int tok;
    if (ch == 0) tok = (t + 1) >> 1;
    else         tok = (t == NSTEP - 1) ? (S_ - 1) : ((t & 1) ? (t >> 1) : (t >> 1) + 1);

    asm volatile("" : "+s"(soff));
    const short* p6 = w6b + soff;
    const short* p7 = w7b + soff;

    // first half of xz addends (rest loaded after phase A to cap live range)
    const short* xp = xzb + (long)tok * 65536;
    u16x8 xq0 = *(const u16x8*)(xp);
    u16x8 xq1 = *(const u16x8*)(xp + 8);

    // stream batch 1 (ks 0..3)
    short8 s6[4], s7[4];
#pragma unroll
    for (int k = 0; k < 4; ++k) {
      s6[k] = *(const short8*)(p6 + k * 32);
      s7[k] = *(const short8*)(p7 + k * 32);
    }

    f32x4 acc[8];
#pragma unroll
    for (int mt = 0; mt < 8; ++mt) acc[mt] = (f32x4){0.f, 0.f, 0.f, 0.f};

    const int pr = ((t + 1) & 1) * 8192;

    // ---- phase A: ks 0..3 ----
#pragma unroll
    for (int ks = 0; ks < 4; ++ks) {
      int koff = ks * 64 + l4 * 16;
      short8 hfr = *(const short8*)(hlr + pr + bloc * 512 + (koff ^ swz));
      short8 w4  = *(const short8*)(wlc + (koff ^ swz));
      short8 w5  = *(const short8*)(wlc + 8192 + (koff ^ swz));
      mfma_ag(acc[0], ah[0][ks], hfr);
      mfma_ag(acc[1], ah[1][ks], hfr);
      mfma_ag(acc[2], ah[2][ks], hfr);
      mfma_ag(acc[3], ah[3][ks], hfr);
      acc[4] = __builtin_amdgcn_mfma_f32_16x16x32_bf16(w4, hfr, acc[4], 0, 0, 0);
      acc[5] = __builtin_amdgcn_mfma_f32_16x16x32_bf16(w5, hfr, acc[5], 0, 0, 0);
      acc[6] = __builtin_amdgcn_mfma_f32_16x16x32_bf16(s6[ks], hfr, acc[6], 0, 0, 0);
      acc[7] = __builtin_amdgcn_mfma_f32_16x16x32_bf16(s7[ks], hfr, acc[7], 0, 0, 0);
    }

    // second half of xz + stream batch 2 (ks 4..7)
    u16x8 xq2 = *(const u16x8*)(xp + 4096);
    u16x8 xq3 = *(const u16x8*)(xp + 4104);
    short8 t6[4], t7[4];
#pragma unroll
    for (int k = 0; k < 4; ++k) {
      t6[k] = *(const short8*)(p6 + 128 + k * 32);
      t7[k] = *(const short8*)(p7 + 128 + k * 32);
    }

    // ---- phase B: ks 4..7 ----
#pragma unroll
    for (int ks = 4; ks < 8; ++ks) {
      int koff = ks * 64 + l4 * 16;
      short8 hfr = *(const short8*)(hlr + pr + bloc * 512 + (koff ^ swz));
      short8 w4  = *(const short8*)(wlc + (koff ^ swz));
      short8 w5  = *(const short8*)(wlc + 8192 + (koff ^ swz));
      mfma_ag(acc[0], ah[0][ks], hfr);
      mfma_ag(acc[1], ah[1][ks], hfr);
      mfma_ag(acc[2], ah[2][ks], hfr);
      mfma_ag(acc[3], ah[3][ks], hfr);
      acc[4] = __builtin_amdgcn_mfma_f32_16x16x32_bf16(w4, hfr, acc[4], 0, 0, 0);
      acc[5] = __builtin_amdgcn_mfma_f32_16x16x32_bf16(w5, hfr, acc[5], 0, 0, 0);
      acc[6] = __builtin_amdgcn_mfma_f32_16x16x32_bf16(t6[ks - 4], hfr, acc[6], 0, 0, 0);
      acc[7] = __builtin_amdgcn_mfma_f32_16x16x32_bf16(t7[ks - 4], hfr, acc[7], 0, 0, 0);
    }

    // hazard guard: asm-MFMA dests (acc0-3) must age before VALU reads; the "+v"
    // outputs also order the gate phase after these nops.
    asm volatile("s_nop 7\n\ts_nop 7"
                 : "+v"(acc[0]), "+v"(acc[1]), "+v"(acc[2]), "+v"(acc[3]));

    // ---- gates / state / h write ----
    unsigned short hv[8];
#pragma unroll
    for (int mt = 0; mt < 8; ++mt) {
      const u16x8& q = (mt < 2) ? xq0 : (mt < 4) ? xq1 : (mt < 6) ? xq2 : xq3;
      const int o = (mt & 1) * 4;
      float zi = acc[mt][0] + bf2f(q[o]);
      float zf = acc[mt][1] + bf2f(q[o + 1]);
      float zg = acc[mt][2] + bf2f(q[o + 2]);
      float zo = acc[mt][3] + bf2f(q[o + 3]);
      float cc = cst[mt];
      cc = sigm(zf) * cc + sigm(zi) * tanh_(zg);
      float hh = sigm(zo) * tanh_(cc);
      cst[mt] = cc;
      hmax[mt] = fmaxf(hmax[mt], hh);
      hv[mt] = f2bf(hh);
    }
    {
      char* hw = hlw + (t & 1) * 8192 + bloc * 512;
      u16x4 a = {hv[0], hv[1], hv[2], hv[3]};
      u16x4 b = {hv[4], hv[5], hv[6], hv[7]};
      *(u16x4*)(hw + ((wave * 64 + l4 * 8) ^ swz)) = a;
      *(u16x4*)(hw + ((wave * 64 + l4 * 8 + 32) ^ swz)) = b;
    }

    __syncthreads();
  }

#pragma unroll
  for (int mt = 0; mt < 8; ++mt) {
    int jc = wave * 32 + mt * 4 + l4;
    out[(long)bglob * (2 * H_) + ch * H_ + jc] = hmax[mt];
  }
}

// ---------- fallback (no xz workspace): v3 structure, MODE 0 ----------
__global__ __launch_bounds__(1024, 4) void lstm_fb(
    const short* __restrict__ x_bf, const short* __restrict__ wx,
    const short* __restrict__ wh, const float* __restrict__ bias_p,
    float* __restrict__ out)
{
  const int ch = blockIdx.x >> 2;
  const int bs = blockIdx.x & 3;
  const int tid = threadIdx.x;
  const int wave = tid >> 6, lane = tid & 63;
  const int l15 = lane & 15, l4 = lane >> 4;
  const int bloc = l15;
  const int bglob = bs * 16 + l15;

  __shared__ short w_lds[16 * 16 * 256];
  __shared__ short h_lds[2 * 16 * 256];

  const short* whc = wh + (long)ch * 1024 * 256;
  const short* wxc = wx + (long)ch * 1024 * 256;

  {
    char* wl = (char*)w_lds;
#pragma unroll
    for (int c = 0; c < 8; ++c) {
      int chunk = c * 64 + lane;
      int row = chunk >> 5;
      int c16 = chunk & 31;
      short8 v = *(const short8*)(whc + (long)(wave * 64 + 48 + row) * 256 + c16 * 8);
      int boff = wave * 8192 + row * 512 + ((c16 * 16) ^ ((row & 7) << 4));
      *(short8*)(wl + boff) = v;
    }
    for (int i = tid; i < 2 * 16 * 256; i += 1024) h_lds[i] = 0;
  }

  short8 ah[3][8];
#pragma unroll
  for (int mt = 0; mt < 3; ++mt)
#pragma unroll
    for (int ks = 0; ks < 8; ++ks)
      ah[mt][ks] = *(const short8*)(whc + (long)(wave * 64 + mt * 16 + l15) * 256 + ks * 32 + l4 * 8);

  f32x4 bias4v[4];
#pragma unroll
  for (int mt = 0; mt < 4; ++mt)
    bias4v[mt] = *(const f32x4*)(bias_p + ch * 1024 + (wave * 16 + mt * 4 + l4) * 4);

  float cst[4], hmax[4];
#pragma unroll
  for (int mt = 0; mt < 4; ++mt) { cst[mt] = 0.f; hmax[mt] = -2.f; }

  __syncthreads();

  const char* hlr = (const char*)h_lds;
  const char* wlr = (const char*)w_lds;
  char* hlw = (char*)h_lds;
  const int swzb = (bloc & 7) << 4;
  const int wboff = wave * 8192 + l15 * 512;
  const int q0b = (wave * 16 + l4 * 4) * 2;

  for (int t = 0; t < NSTEP; ++t) {
    int tok;
    if (ch == 0) tok = (t + 1) >> 1;
    else         tok = (t == NSTEP - 1) ? (S_ - 1) : ((t & 1) ? (t >> 1) : (t >> 1) + 1);

    f32x4 acc[4];
#pragma unroll
    for (int mt = 0; mt < 4; ++mt) acc[mt] = (f32x4){0.f, 0.f, 0.f, 0.f};

    const short* xr = x_bf + ((long)tok * B_ + bglob) * E_;
#pragma unroll
    for (int ks = 0; ks < 8; ++ks) {
      int k0 = ks * 32 + l4 * 8;
      short8 bx = *(const short8*)(xr + k0);
#pragma unroll
      for (int mt = 0; mt < 4; ++mt) {
        short8 axf = *(const short8*)(wxc + (long)(wave * 64 + mt * 16 + l15) * 256 + k0);
        acc[mt] = __builtin_amdgcn_mfma_f32_16x16x32_bf16(axf, bx, acc[mt], 0, 0, 0);
      }
    }

    const int hbase = (((t + 1) & 1) * 8192) + bloc * 512;
#pragma unroll
    for (int ks = 0; ks < 8; ++ks) {
      int koff = ks * 64 + l4 * 16;
      short8 hfr = *(const short8*)(hlr + hbase + (koff ^ swzb));
      acc[0] = __builtin_amdgcn_mfma_f32_16x16x32_bf16(ah[0][ks], hfr, acc[0], 0, 0, 0);
      acc[1] = __builtin_amdgcn_mfma_f32_16x16x32_bf16(ah[1][ks], hfr, acc[1], 0, 0, 0);
      acc[2] = __builtin_amdgcn_mfma_f32_16x16x32_bf16(ah[2][ks], hfr, acc[2], 0, 0, 0);
      short8 wfr = *(const short8*)(wlr + wboff + (koff ^ ((l15 & 7) << 4)));
      acc[3] = __builtin_amdgcn_mfma_f32_16x16x32_bf16(wfr, hfr, acc[3], 0, 0, 0);
    }

    unsigned short hv[4];
#pragma unroll
    for (int mt = 0; mt < 4; ++mt) {
      float zi = acc[mt][0] + bias4v[mt][0];
      float zf = acc[mt][1] + bias4v[mt][1];
      float zg = acc[mt][2] + bias4v[mt][2];
      float zo = acc[mt][3] + bias4v[mt][3];
      float cc = cst[mt];
      cc = sigm(zf) * cc + sigm(zi) * tanh_(zg);
      float hh = sigm(zo) * tanh_(cc);
      cst[mt] = cc;
      hmax[mt] = fmaxf(hmax[mt], hh);
      hv[mt] = f2bf(hh);
    }
    {
      u16x4 hw4 = {hv[0], hv[1], hv[2], hv[3]};
      int wb = ((t & 1) * 8192) + bloc * 512 + (q0b ^ swzb);
      *(u16x4*)(hlw + wb) = hw4;
    }

    __syncthreads();
  }

#pragma unroll
  for (int mt = 0; mt < 4; ++mt) {
    int jc = wave * 16 + mt * 4 + l4;
    out[(long)bglob * (2 * H_) + ch * H_ + jc] = hmax[mt];
  }
}

extern "C" void kernel_launch(void* const* d_in, const int* in_sizes, int n_in,
                              void* d_out, int out_size, void* d_ws, size_t ws_size,
                              hipStream_t stream) {
  const float* x     = (const float*)d_in[0];
  const float* wih_f = (const float*)d_in[1];
  const float* whh_f = (const float*)d_in[2];
  const float* bih_f = (const float*)d_in[3];
  const float* bhh_f = (const float*)d_in[4];
  const float* wih_b = (const float*)d_in[5];
  const float* whh_b = (const float*)d_in[6];
  const float* bih_b = (const float*)d_in[7];
  const float* bhh_b = (const float*)d_in[8];

  char* ws = (char*)d_ws;
  short* x_bf   = (short*)(ws);                 // 16,777,216 B
  short* wx     = (short*)(ws + 16777216);      //  1,048,576 B
  short* wh     = (short*)(ws + 17825792);      //  1,048,576 B
  float* bias_p = (float*)(ws + 18874368);      //      8,192 B
  short* xz     = (short*)(ws + 18882560);      // 134,217,728 B (bf16)

  const size_t NEED_XZ = 18882560UL + 134217728UL;   // 153,100,288
  if (ws_size < 18882560UL) return;

  prep3<<<2048, 256, 0, stream>>>(x, wih_f, whh_f, bih_f, bhh_f,
                                  wih_b, whh_b, bih_b, bhh_b,
                                  x_bf, wx, wh, bias_p);

  float* outp = (float*)d_out;
  if (ws_size >= NEED_XZ) {
    xz_gemm3<<<1024, 512, 0, stream>>>(x_bf, wx, bias_p, xz);
    lstm7<<<8, 512, 0, stream>>>(wh, xz, outp);
  } else {
    lstm_fb<<<8, 1024, 0, stream>>>(x_bf, wx, wh, bias_p, outp);
  }
}

// Round 9
// 3376.317 us; speedup vs baseline: 4.2668x; 2.3556x over previous
//
#include <hip/hip_runtime.h>

typedef __attribute__((ext_vector_type(8))) short short8;
typedef __attribute__((ext_vector_type(4))) float f32x4;
typedef __attribute__((ext_vector_type(4))) unsigned short u16x4;

#define S_ 512
#define B_ 64
#define E_ 256
#define H_ 256
#define NSTEP 1023  // 2*S - 1 sequential cell steps per chain

// ---------- helpers ----------
__device__ __forceinline__ unsigned short f2bf(float f) {
  unsigned u = __builtin_bit_cast(unsigned, f);
  return (unsigned short)((u + 0x7fffu + ((u >> 16) & 1u)) >> 16);  // RNE
}
__device__ __forceinline__ float bf2f(unsigned short h) {
  unsigned u = ((unsigned)h) << 16;
  return __builtin_bit_cast(float, u);
}
__device__ __forceinline__ float sigm(float x) { return 1.f / (1.f + __expf(-x)); }
__device__ __forceinline__ float tanh_(float x) {
  x = fminf(fmaxf(x, -15.f), 15.f);
  float e = __expf(-2.f * x);
  return (1.f - e) / (1.f + e);
}

// ---------- prep: x -> bf16; wx/wh packed rows p=jc*4+gate, NATURAL columns; bias combined ----------
__global__ __launch_bounds__(256) void prep9(
    const float* __restrict__ x,
    const float* __restrict__ wih_f, const float* __restrict__ whh_f,
    const float* __restrict__ bih_f, const float* __restrict__ bhh_f,
    const float* __restrict__ wih_b, const float* __restrict__ whh_b,
    const float* __restrict__ bih_b, const float* __restrict__ bhh_b,
    short* __restrict__ x_bf, short* __restrict__ wx, short* __restrict__ wh,
    float* __restrict__ bias_p)
{
  long i0 = (long)blockIdx.x * blockDim.x + threadIdx.x;
  long stride = (long)gridDim.x * blockDim.x;
  const long NX = (long)S_ * B_ * E_;
  const long NW = 2L * 1024 * 256;
  const long NB = 2L * 1024;

  for (long i = i0; i < NX; i += stride) x_bf[i] = (short)f2bf(x[i]);

  for (long i = i0; i < NW; i += stride) {
    int ch  = (int)(i >> 18);
    int rem = (int)(i & 262143);
    int p   = rem >> 8;              // packed row 0..1023
    int k   = rem & 255;
    int jc  = p >> 2, g = p & 3;
    long j  = (long)(g * 256 + jc);  // original gate row
    wx[i] = (short)f2bf((ch ? wih_b : wih_f)[j * 256 + k]);
    wh[i] = (short)f2bf((ch ? whh_b : whh_f)[j * 256 + k]);
  }

  for (long i = i0; i < NB; i += stride) {
    int ch = (int)(i >> 10);
    int p  = (int)(i & 1023);
    int jc = p >> 2, g = p & 3;
    int j  = g * 256 + jc;
    bias_p[i] = ch ? (bih_b[j] + bhh_b[j]) : (bih_f[j] + bhh_f[j]);
  }
}

// ---------- xz precompute (bias folded), bf16; layout xz[ch][t][jc 256][b 64][g 4] ----------
__global__ __launch_bounds__(512, 2) void xz_gemm9(
    const short* __restrict__ x_bf, const short* __restrict__ wx,
    const float* __restrict__ bias_p, short* __restrict__ xz)
{
  const int bid = blockIdx.x;
  const int ch = bid >> 9, t = bid & 511;
  const int tid = threadIdx.x;
  const int wave = tid >> 6, lane = tid & 63;
  const int l15 = lane & 15, l4 = lane >> 4;

  const short* W = wx + (long)ch * 1024 * 256;
  const short* X = x_bf + (long)t * B_ * E_;

  f32x4 acc[8][4];
#pragma unroll
  for (int mt = 0; mt < 8; ++mt)
#pragma unroll
    for (int nt = 0; nt < 4; ++nt) acc[mt][nt] = (f32x4){0.f, 0.f, 0.f, 0.f};

#pragma unroll
  for (int ks = 0; ks < 8; ++ks) {
    int k0 = ks * 32 + l4 * 8;
    short8 bfr[4];
#pragma unroll
    for (int nt = 0; nt < 4; ++nt)
      bfr[nt] = *(const short8*)(X + (long)(nt * 16 + l15) * E_ + k0);
#pragma unroll
    for (int mt = 0; mt < 8; ++mt) {
      int p = (wave * 8 + mt) * 16 + l15;
      short8 af = *(const short8*)(W + (long)p * 256 + k0);
#pragma unroll
      for (int nt = 0; nt < 4; ++nt)
        acc[mt][nt] = __builtin_amdgcn_mfma_f32_16x16x32_bf16(af, bfr[nt], acc[mt][nt], 0, 0, 0);
    }
  }

#pragma unroll
  for (int mt = 0; mt < 8; ++mt) {
    int jc = (wave * 8 + mt) * 4 + l4;
    f32x4 b4 = *(const f32x4*)(bias_p + ch * 1024 + jc * 4);
#pragma unroll
    for (int nt = 0; nt < 4; ++nt) {
      int b = nt * 16 + l15;
      u16x4 v;
#pragma unroll
      for (int g = 0; g < 4; ++g) v[g] = f2bf(acc[mt][nt][g] + b4[g]);
      long off = (((long)(ch * 512 + t) * 256 + jc) * 64 + b) * 4;
      *(u16x4*)(xz + off) = v;
    }
  }
}

// ---------- v9 LSTM: 32 blocks = (ch 2) x (bs 4) x (role 4); 512 threads each ----------
// Block owns packed rows [role*256,+256) (= jc [role*64,+64)) and batch cols [bs*16,+16).
// Weights fully register-resident per wave (ah[2][8] = 64 VGPR; total demand ~105 < 128).
// Cross-block h exchange within the 4-role group via L3 (sc1 loads/stores; no cache flushes;
// no XCD/dispatch assumptions -- all 32 blocks trivially co-resident).
__global__ __launch_bounds__(512) void lstm9(
    const short* __restrict__ wh, const short* __restrict__ xz,
    short* __restrict__ h_glob,   // [ch][parity][b 64][col 256] bf16
    int* __restrict__ flags,      // [ch][bs][role]
    float* __restrict__ out)      // [64][512]
{
  const int bid  = blockIdx.x;
  const int ch   = bid >> 4;
  const int bs   = (bid >> 2) & 3;
  const int role = bid & 3;
  const int tid  = threadIdx.x;
  const int wave = tid >> 6, lane = tid & 63;
  const int l15 = lane & 15, l4 = lane >> 4;

  __shared__ short hin[16 * 256];   // 8 KB: staged h_{t-1} (rows = local b), XOR-swizzled
  __shared__ short hout[16 * 64];   // 2 KB: this block's new h cols, XOR-swizzled

  const short* whc = wh + (long)ch * 1024 * 256;

  // register-resident weight tiles: rows role*256 + wave*32 + mt*16 + l15
  short8 ah[2][8];
#pragma unroll
  for (int mt = 0; mt < 2; ++mt)
#pragma unroll
    for (int ks = 0; ks < 8; ++ks)
      ah[mt][ks] = *(const short8*)(whc + (long)(role * 256 + wave * 32 + mt * 16 + l15) * 256 + ks * 32 + l4 * 8);

  float cst[2], hmax[2];
#pragma unroll
  for (int mt = 0; mt < 2; ++mt) { cst[mt] = 0.f; hmax[mt] = -2.f; }

  int* fl = flags + (ch * 4 + bs) * 4;
  short* hg = h_glob + (long)ch * 2 * B_ * H_;
  const int swzr = (l15 & 7) << 4;

  for (int t = 0; t < NSTEP; ++t) {
    int tok;
    if (ch == 0) tok = (t + 1) >> 1;
    else         tok = (t == NSTEP - 1) ? (S_ - 1) : ((t & 1) ? (t >> 1) : (t >> 1) + 1);

    // xz addends (normal cached loads; constant data)
    u16x4 xq[2];
#pragma unroll
    for (int mt = 0; mt < 2; ++mt) {
      int jc = role * 64 + wave * 8 + mt * 4 + l4;
      long off = (((long)(ch * 512 + tok) * 256 + jc) * 64 + (bs * 16 + l15)) * 4;
      xq[mt] = *(const u16x4*)(xz + off);
    }

    // ---- poll group flags >= t (L3, sc1) ----
    {
      const int* fla = fl + (lane & 3);
      int v;
      do {
        asm volatile("global_load_dword %0, %1, off sc1\n\ts_waitcnt vmcnt(0)"
                     : "=v"(v) : "v"(fla) : "memory");
      } while (__ballot(v < t));
    }

    // ---- stage-in h_{t-1} (8 KB for our 16 b-rows) from L3 into LDS ----
    {
      int bloc = tid >> 5, c8 = (tid & 31) * 8;  // 8-elem chunks
      const short* ga = hg + (long)((t + 1) & 1) * B_ * H_ + (bs * 16 + bloc) * 256 + c8;
      short8 hv;
      asm volatile("global_load_dwordx4 %0, %1, off sc1\n\ts_waitcnt vmcnt(0)"
                   : "=v"(hv) : "v"(ga) : "memory");
      *(short8*)((char*)hin + bloc * 512 + ((c8 * 2) ^ ((bloc & 7) << 4))) = hv;
    }
    __syncthreads();

    // ---- recurrent MFMAs: 2 M-tiles x 8 k-steps ----
    f32x4 acc[2];
    acc[0] = (f32x4){0.f, 0.f, 0.f, 0.f};
    acc[1] = (f32x4){0.f, 0.f, 0.f, 0.f};
    const char* hr = (const char*)hin + l15 * 512;
#pragma unroll
    for (int ks = 0; ks < 8; ++ks) {
      short8 hfr = *(const short8*)(hr + ((ks * 64 + l4 * 16) ^ swzr));
      acc[0] = __builtin_amdgcn_mfma_f32_16x16x32_bf16(ah[0][ks], hfr, acc[0], 0, 0, 0);
      acc[1] = __builtin_amdgcn_mfma_f32_16x16x32_bf16(ah[1][ks], hfr, acc[1], 0, 0, 0);
    }

    // ---- gates / state; stash new h cols in hout (LDS, swizzled) ----
#pragma unroll
    for (int mt = 0; mt < 2; ++mt) {
      float zi = acc[mt][0] + bf2f(xq[mt][0]);
      float zf = acc[mt][1] + bf2f(xq[mt][1]);
      float zg = acc[mt][2] + bf2f(xq[mt][2]);
      float zo = acc[mt][3] + bf2f(xq[mt][3]);
      float cc = cst[mt];
      cc = sigm(zf) * cc + sigm(zi) * tanh_(zg);
      float hh = sigm(zo) * tanh_(cc);
      cst[mt] = cc;
      hmax[mt] = fmaxf(hmax[mt], hh);
      int lc = wave * 8 + mt * 4 + l4;  // local col 0..63
      *(short*)((char*)hout + l15 * 128 + ((lc * 2) ^ ((l15 & 7) << 4))) = (short)f2bf(hh);
    }
    __syncthreads();

    // ---- write-out our 2 KB h rectangle to L3 (sc1), drain, publish flag ----
    if (tid < 256) {
      int bloc = tid >> 4, c4 = tid & 15;  // 8B chunks
      unsigned long long val =
          *(const unsigned long long*)((const char*)hout + bloc * 128 + ((c4 * 8) ^ ((bloc & 7) << 4)));
      short* ga = hg + (long)(t & 1) * B_ * H_ + (bs * 16 + bloc) * 256 + role * 64 + c4 * 4;
      asm volatile("global_store_dwordx2 %0, %1, off sc1\n\ts_waitcnt vmcnt(0)"
                   :: "v"(ga), "v"(val) : "memory");
    }
    __syncthreads();
    if (tid == 0) {
      int* fa = fl + role;
      int tv = t + 1;
      asm volatile("global_store_dword %0, %1, off sc1" :: "v"(fa), "v"(tv) : "memory");
    }
  }

  // ---- final: running maxes ----
#pragma unroll
  for (int mt = 0; mt < 2; ++mt) {
    int jc = role * 64 + wave * 8 + mt * 4 + l4;
    out[(long)(bs * 16 + l15) * (2 * H_) + ch * H_ + jc] = hmax[mt];
  }
}

extern "C" void kernel_launch(void* const* d_in, const int* in_sizes, int n_in,
                              void* d_out, int out_size, void* d_ws, size_t ws_size,
                              hipStream_t stream) {
  const float* x     = (const float*)d_in[0];
  const float* wih_f = (const float*)d_in[1];
  const float* whh_f = (const float*)d_in[2];
  const float* bih_f = (const float*)d_in[3];
  const float* bhh_f = (const float*)d_in[4];
  const float* wih_b = (const float*)d_in[5];
  const float* whh_b = (const float*)d_in[6];
  const float* bih_b = (const float*)d_in[7];
  const float* bhh_b = (const float*)d_in[8];

  char* ws = (char*)d_ws;
  short* x_bf   = (short*)(ws);                 // 16,777,216 B (dead after xz_gemm9)
  short* h_glob = (short*)(ws);                 // 131,072 B  (reuses x_bf region)
  int*   flags  = (int*)  (ws + 131072);        //     128 B
  short* wx     = (short*)(ws + 16777216);      //  1,048,576 B
  short* wh     = (short*)(ws + 17825792);      //  1,048,576 B
  float* bias_p = (float*)(ws + 18874368);      //      8,192 B
  short* xz     = (short*)(ws + 18882560);      // 134,217,728 B (bf16)

  const size_t NEED = 18882560UL + 134217728UL;   // 153,100,288 (same as prior rounds)
  if (ws_size < NEED) return;

  prep9<<<2048, 256, 0, stream>>>(x, wih_f, whh_f, bih_f, bhh_f,
                                  wih_b, whh_b, bih_b, bhh_b,
                                  x_bf, wx, wh, bias_p);
  xz_gemm9<<<1024, 512, 0, stream>>>(x_bf, wx, bias_p, xz);

  // x_bf is dead now; zero h state + flags in its place, then run the chains.
  hipMemsetAsync(ws, 0, 131200, stream);

  lstm9<<<32, 512, 0, stream>>>(wh, xz, h_glob, flags, (float*)d_out);
}

// Round 10
// 1823.648 us; speedup vs baseline: 7.8996x; 1.8514x over previous
//
#include <hip/hip_runtime.h>

typedef __attribute__((ext_vector_type(8))) short short8;
typedef __attribute__((ext_vector_type(4))) float f32x4;
typedef __attribute__((ext_vector_type(4))) unsigned short u16x4;
typedef __attribute__((ext_vector_type(4))) unsigned int u32x4;

#define S_ 512
#define B_ 64
#define E_ 256
#define H_ 256
#define NSTEP 1023  // 2*S - 1 sequential cell steps per chain

// ---------- helpers ----------
__device__ __forceinline__ unsigned short f2bf(float f) {
  unsigned u = __builtin_bit_cast(unsigned, f);
  return (unsigned short)((u + 0x7fffu + ((u >> 16) & 1u)) >> 16);  // RNE
}
__device__ __forceinline__ float bf2f(unsigned short h) {
  unsigned u = ((unsigned)h) << 16;
  return __builtin_bit_cast(float, u);
}
__device__ __forceinline__ float sigm(float x) { return 1.f / (1.f + __expf(-x)); }
__device__ __forceinline__ float tanh_(float x) {
  x = fminf(fmaxf(x, -15.f), 15.f);
  float e = __expf(-2.f * x);
  return (1.f - e) / (1.f + e);
}

// ---------- prep: x -> bf16; wx/wh packed rows p=jc*4+gate, NATURAL columns; bias combined ----------
__global__ __launch_bounds__(256) void prep9(
    const float* __restrict__ x,
    const float* __restrict__ wih_f, const float* __restrict__ whh_f,
    const float* __restrict__ bih_f, const float* __restrict__ bhh_f,
    const float* __restrict__ wih_b, const float* __restrict__ whh_b,
    const float* __restrict__ bih_b, const float* __restrict__ bhh_b,
    short* __restrict__ x_bf, short* __restrict__ wx, short* __restrict__ wh,
    float* __restrict__ bias_p)
{
  long i0 = (long)blockIdx.x * blockDim.x + threadIdx.x;
  long stride = (long)gridDim.x * blockDim.x;
  const long NX = (long)S_ * B_ * E_;
  const long NW = 2L * 1024 * 256;
  const long NB = 2L * 1024;

  for (long i = i0; i < NX; i += stride) x_bf[i] = (short)f2bf(x[i]);

  for (long i = i0; i < NW; i += stride) {
    int ch  = (int)(i >> 18);
    int rem = (int)(i & 262143);
    int p   = rem >> 8;              // packed row 0..1023
    int k   = rem & 255;
    int jc  = p >> 2, g = p & 3;
    long j  = (long)(g * 256 + jc);  // original gate row
    wx[i] = (short)f2bf((ch ? wih_b : wih_f)[j * 256 + k]);
    wh[i] = (short)f2bf((ch ? whh_b : whh_f)[j * 256 + k]);
  }

  for (long i = i0; i < NB; i += stride) {
    int ch = (int)(i >> 10);
    int p  = (int)(i & 1023);
    int jc = p >> 2, g = p & 3;
    int j  = g * 256 + jc;
    bias_p[i] = ch ? (bih_b[j] + bhh_b[j]) : (bih_f[j] + bhh_f[j]);
  }
}

// ---------- xz precompute (bias folded), bf16; layout xz[ch][t][jc 256][b 64][g 4] ----------
__global__ __launch_bounds__(512, 2) void xz_gemm9(
    const short* __restrict__ x_bf, const short* __restrict__ wx,
    const float* __restrict__ bias_p, short* __restrict__ xz)
{
  const int bid = blockIdx.x;
  const int ch = bid >> 9, t = bid & 511;
  const int tid = threadIdx.x;
  const int wave = tid >> 6, lane = tid & 63;
  const int l15 = lane & 15, l4 = lane >> 4;

  const short* W = wx + (long)ch * 1024 * 256;
  const short* X = x_bf + (long)t * B_ * E_;

  f32x4 acc[8][4];
#pragma unroll
  for (int mt = 0; mt < 8; ++mt)
#pragma unroll
    for (int nt = 0; nt < 4; ++nt) acc[mt][nt] = (f32x4){0.f, 0.f, 0.f, 0.f};

#pragma unroll
  for (int ks = 0; ks < 8; ++ks) {
    int k0 = ks * 32 + l4 * 8;
    short8 bfr[4];
#pragma unroll
    for (int nt = 0; nt < 4; ++nt)
      bfr[nt] = *(const short8*)(X + (long)(nt * 16 + l15) * E_ + k0);
#pragma unroll
    for (int mt = 0; mt < 8; ++mt) {
      int p = (wave * 8 + mt) * 16 + l15;
      short8 af = *(const short8*)(W + (long)p * 256 + k0);
#pragma unroll
      for (int nt = 0; nt < 4; ++nt)
        acc[mt][nt] = __builtin_amdgcn_mfma_f32_16x16x32_bf16(af, bfr[nt], acc[mt][nt], 0, 0, 0);
    }
  }

#pragma unroll
  for (int mt = 0; mt < 8; ++mt) {
    int jc = (wave * 8 + mt) * 4 + l4;
    f32x4 b4 = *(const f32x4*)(bias_p + ch * 1024 + jc * 4);
#pragma unroll
    for (int nt = 0; nt < 4; ++nt) {
      int b = nt * 16 + l15;
      u16x4 v;
#pragma unroll
      for (int g = 0; g < 4; ++g) v[g] = f2bf(acc[mt][nt][g] + b4[g]);
      long off = (((long)(ch * 512 + t) * 256 + jc) * 64 + b) * 4;
      *(u16x4*)(xz + off) = v;
    }
  }
}

// ---------- v10 LSTM: 32 blocks = (ch 2) x (bs 4) x (role 4); flag-free poison ring ----------
// Ring: hring[slot 4][ch 2][b 64][col 256] bf16 (64 KB/slot). Poison short = 0xFFFF
// (f2bf(finite) can never produce it). Producer step t: poison own rect in slot (t+1)&3
// (drained by the spin's vmcnt before data goes out), spin-load slot (t-1)&3 until no
// dword == 0xFFFFFFFF (data IS the flag), compute, store data to slot t&3 with NO drain
// (latency overlaps the next spin). Induction: consumer saw data(u-2) => producer's
// poison(u-1) [ordered before data(u-2) by the spin vmcnt] is visible => slot (u-1)
// can never show stale pre-poison data. Skew<=1 keeps {t-1,t,t+1,t+2} distinct mod 4.
__global__ __launch_bounds__(512) void lstm10(
    const short* __restrict__ wh, const short* __restrict__ xz,
    short* __restrict__ hring, float* __restrict__ out)
{
  const int bid  = blockIdx.x;
  const int ch   = bid >> 4;
  const int bs   = (bid >> 2) & 3;
  const int role = bid & 3;
  const int tid  = threadIdx.x;
  const int wave = tid >> 6, lane = tid & 63;
  const int l15 = lane & 15, l4 = lane >> 4;

  __shared__ short hin[16 * 256];   // 8 KB: staged h_{t-1}, XOR-swizzled
  __shared__ short hout[16 * 64];   // 2 KB: this block's new h cols, XOR-swizzled

  const short* whc = wh + (long)ch * 1024 * 256;

  // register-resident weight tiles: rows role*256 + wave*32 + mt*16 + l15
  short8 ah[2][8];
#pragma unroll
  for (int mt = 0; mt < 2; ++mt)
#pragma unroll
    for (int ks = 0; ks < 8; ++ks)
      ah[mt][ks] = *(const short8*)(whc + (long)(role * 256 + wave * 32 + mt * 16 + l15) * 256 + ks * 32 + l4 * 8);

  float cst[2], hmax[2];
#pragma unroll
  for (int mt = 0; mt < 2; ++mt) { cst[mt] = 0.f; hmax[mt] = -2.f; }

  short* rb = hring + ch * 16384;        // ch base (shorts)
  const int swzr = (l15 & 7) << 4;

  // per-thread store/poison coords (tid<256): 16 rows x 16 chunks of 8B
  const int sb = tid >> 4, sc = tid & 15;
  // per-thread spin/stage coords: 16 rows x 32 chunks of 16B
  const int pb = tid >> 5, pc = tid & 31;

  for (int t = 0; t < NSTEP; ++t) {
    int tok;
    if (ch == 0) tok = (t + 1) >> 1;
    else         tok = (t == NSTEP - 1) ? (S_ - 1) : ((t & 1) ? (t >> 1) : (t >> 1) + 1);

    // xz addends (normal cached loads; constant data)
    u16x4 xq[2];
#pragma unroll
    for (int mt = 0; mt < 2; ++mt) {
      int jc = role * 64 + wave * 8 + mt * 4 + l4;
      long off = (((long)(ch * 512 + tok) * 256 + jc) * 64 + (bs * 16 + l15)) * 4;
      xq[mt] = *(const u16x4*)(xz + off);
    }

    // ---- poison own rectangle in slot (t+1)&3 (drained by the spin's vmcnt) ----
    if (tid < 256) {
      short* pa = rb + ((t + 1) & 3) * 32768 + (bs * 16 + sb) * 256 + role * 64 + sc * 4;
      unsigned long long pv = 0xFFFFFFFFFFFFFFFFull;
      asm volatile("global_store_dwordx2 %0, %1, off sc1" :: "v"(pa), "v"(pv) : "memory");
    }

    // ---- spin+stage h_{t-1} from slot (t+3)&3: data IS the flag ----
    {
      const short* ga = rb + ((t + 3) & 3) * 32768 + (bs * 16 + pb) * 256 + pc * 8;
      short8 hv;
      int ok;
      do {
        asm volatile("global_load_dwordx4 %0, %1, off sc1\n\ts_waitcnt vmcnt(0)"
                     : "=v"(hv) : "v"(ga) : "memory");
        u32x4 dv = __builtin_bit_cast(u32x4, hv);
        ok = (dv.x != 0xFFFFFFFFu) & (dv.y != 0xFFFFFFFFu) &
             (dv.z != 0xFFFFFFFFu) & (dv.w != 0xFFFFFFFFu);
      } while (__ballot(!ok));
      *(short8*)((char*)hin + pb * 512 + ((pc * 16) ^ ((pb & 7) << 4))) = hv;
    }
    __syncthreads();

    // ---- recurrent MFMAs: 2 M-tiles x 8 k-steps ----
    f32x4 acc[2];
    acc[0] = (f32x4){0.f, 0.f, 0.f, 0.f};
    acc[1] = (f32x4){0.f, 0.f, 0.f, 0.f};
    const char* hr = (const char*)hin + l15 * 512;
#pragma unroll
    for (int ks = 0; ks < 8; ++ks) {
      short8 hfr = *(const short8*)(hr + ((ks * 64 + l4 * 16) ^ swzr));
      acc[0] = __builtin_amdgcn_mfma_f32_16x16x32_bf16(ah[0][ks], hfr, acc[0], 0, 0, 0);
      acc[1] = __builtin_amdgcn_mfma_f32_16x16x32_bf16(ah[1][ks], hfr, acc[1], 0, 0, 0);
    }

    // ---- gates / state; stash new h cols in hout (LDS, swizzled) ----
#pragma unroll
    for (int mt = 0; mt < 2; ++mt) {
      float zi = acc[mt][0] + bf2f(xq[mt][0]);
      float zf = acc[mt][1] + bf2f(xq[mt][1]);
      float zg = acc[mt][2] + bf2f(xq[mt][2]);
      float zo = acc[mt][3] + bf2f(xq[mt][3]);
      float cc = cst[mt];
      cc = sigm(zf) * cc + sigm(zi) * tanh_(zg);
      float hh = sigm(zo) * tanh_(cc);
      cst[mt] = cc;
      hmax[mt] = fmaxf(hmax[mt], hh);
      int lc = wave * 8 + mt * 4 + l4;  // local col 0..63
      *(short*)((char*)hout + l15 * 128 + ((lc * 2) ^ ((l15 & 7) << 4))) = (short)f2bf(hh);
    }
    __syncthreads();

    // ---- data store to slot t&3: NO drain, NO flag (visibility rides the next spin) ----
    if (tid < 256) {
      unsigned long long val =
          *(const unsigned long long*)((const char*)hout + sb * 128 + ((sc * 8) ^ ((sb & 7) << 4)));
      short* ga = rb + (t & 3) * 32768 + (bs * 16 + sb) * 256 + role * 64 + sc * 4;
      asm volatile("global_store_dwordx2 %0, %1, off sc1" :: "v"(ga), "v"(val) : "memory");
    }
    // no trailing barrier: hout reuse is ordered by the next iteration's mid barrier,
    // hin reuse by the collective post-gates barrier above.
  }

  // ---- final: running maxes ----
#pragma unroll
  for (int mt = 0; mt < 2; ++mt) {
    int jc = role * 64 + wave * 8 + mt * 4 + l4;
    out[(long)(bs * 16 + l15) * (2 * H_) + ch * H_ + jc] = hmax[mt];
  }
}

extern "C" void kernel_launch(void* const* d_in, const int* in_sizes, int n_in,
                              void* d_out, int out_size, void* d_ws, size_t ws_size,
                              hipStream_t stream) {
  const float* x     = (const float*)d_in[0];
  const float* wih_f = (const float*)d_in[1];
  const float* whh_f = (const float*)d_in[2];
  const float* bih_f = (const float*)d_in[3];
  const float* bhh_f = (const float*)d_in[4];
  const float* wih_b = (const float*)d_in[5];
  const float* whh_b = (const float*)d_in[6];
  const float* bih_b = (const float*)d_in[7];
  const float* bhh_b = (const float*)d_in[8];

  char* ws = (char*)d_ws;
  short* x_bf   = (short*)(ws);                 // 16,777,216 B (dead after xz_gemm9)
  short* hring  = (short*)(ws);                 // 262,144 B ring (reuses x_bf region)
  short* wx     = (short*)(ws + 16777216);      //  1,048,576 B
  short* wh     = (short*)(ws + 17825792);      //  1,048,576 B
  float* bias_p = (float*)(ws + 18874368);      //      8,192 B
  short* xz     = (short*)(ws + 18882560);      // 134,217,728 B (bf16)

  const size_t NEED = 18882560UL + 134217728UL;   // 153,100,288
  if (ws_size < NEED) return;

  prep9<<<2048, 256, 0, stream>>>(x, wih_f, whh_f, bih_f, bhh_f,
                                  wih_b, whh_b, bih_b, bhh_b,
                                  x_bf, wx, wh, bias_p);
  xz_gemm9<<<1024, 512, 0, stream>>>(x_bf, wx, bias_p, xz);

  // x_bf dead; init ring: slots 0..2 = poison (0xFF bytes), slot 3 = zeros (h_{-1} = 0).
  hipMemsetAsync(ws, 0xFF, 196608, stream);
  hipMemsetAsync(ws + 196608, 0, 65536, stream);

  lstm10<<<32, 512, 0, stream>>>(wh, xz, hring, (float*)d_out);
}